// Round 1
// baseline (1023.872 us; speedup 1.0000x reference)
//
#include <hip/hip_runtime.h>
#include <math.h>

static constexpr int S_LEN  = 4096;
static constexpr int DMODEL = 768;
static constexpr int NHEAD  = 12;
static constexpr int HDIM   = 64;

// ---------------------------------------------------------------------------
// C[M,N] = A[M,K] @ B[N,K]^T (+ bias[N])
// 64x64 tile, BK=16, 256 threads, 4x4 accumulator per thread.
// LDS tiles stored k-major [k][m] with stride 68 floats (16B-aligned, 2-way
// max bank aliasing on the float4 read path).
// ---------------------------------------------------------------------------
template<int ADD_BIAS>
__global__ __launch_bounds__(256)
void gemm_abt(const float* __restrict__ A, const float* __restrict__ B,
              const float* __restrict__ bias, float* __restrict__ C,
              int M, int N, int K) {
  __shared__ float As[16][68];   // [k][m]
  __shared__ float Bs[16][68];   // [k][n]
  const int tid = threadIdx.x;
  const int tx = tid & 15;       // n sub-tile
  const int ty = tid >> 4;       // m sub-tile
  const int m0 = blockIdx.y * 64;
  const int n0 = blockIdx.x * 64;
  const int kc = tid & 15;       // loader: k column
  const int r0 = tid >> 4;       // loader: row base

  float acc[4][4] = {};

  for (int k0 = 0; k0 < K; k0 += 16) {
#pragma unroll
    for (int r = 0; r < 4; ++r) {
      As[kc][r0 + 16 * r] = A[(size_t)(m0 + r0 + 16 * r) * K + (k0 + kc)];
      Bs[kc][r0 + 16 * r] = B[(size_t)(n0 + r0 + 16 * r) * K + (k0 + kc)];
    }
    __syncthreads();
#pragma unroll
    for (int kk = 0; kk < 16; ++kk) {
      const float4 a4 = *reinterpret_cast<const float4*>(&As[kk][ty * 4]);
      const float4 b4 = *reinterpret_cast<const float4*>(&Bs[kk][tx * 4]);
      const float av[4] = {a4.x, a4.y, a4.z, a4.w};
      const float bv[4] = {b4.x, b4.y, b4.z, b4.w};
#pragma unroll
      for (int i = 0; i < 4; ++i)
#pragma unroll
        for (int j = 0; j < 4; ++j)
          acc[i][j] = fmaf(av[i], bv[j], acc[i][j]);
    }
    __syncthreads();
  }

  float bj[4] = {0.f, 0.f, 0.f, 0.f};
  if (ADD_BIAS) {
#pragma unroll
    for (int j = 0; j < 4; ++j) bj[j] = bias[n0 + tx * 4 + j];
  }
#pragma unroll
  for (int i = 0; i < 4; ++i) {
    float4 o4;
    o4.x = acc[i][0] + bj[0];
    o4.y = acc[i][1] + bj[1];
    o4.z = acc[i][2] + bj[2];
    o4.w = acc[i][3] + bj[3];
    *reinterpret_cast<float4*>(&C[(size_t)(m0 + ty * 4 + i) * N + n0 + tx * 4]) = o4;
  }
}

// ---------------------------------------------------------------------------
// Flash-style causal attention, fp32.
// grid = (S/64, H); block = 256. Each block: one 64-row Q tile of one head.
// Online softmax state in registers; row reductions via __shfl_xor over the
// 16-lane tx group. KPs buffer double-duty: K tile (d-major) for QK^T, then
// P tile (k-major) for PV. Only the diagonal kv-tile is masked.
// ---------------------------------------------------------------------------
__global__ __launch_bounds__(256)
void attn_fwd(const float* __restrict__ Q, const float* __restrict__ K,
              const float* __restrict__ V, float* __restrict__ O) {
  __shared__ float Qs[64][68];    // [d][q]
  __shared__ float KPs[64][68];   // phase 1: [d][k] (K tile); phase 2: [k][q] (P tile)
  __shared__ float Vs[64][68];    // [k][d]

  const int tid = threadIdx.x;
  const int tx = tid & 15;        // k (phase S) / d (phase PV) sub-tile
  const int ty = tid >> 4;        // q sub-tile
  const int q0 = blockIdx.x * 64;
  const int h  = blockIdx.y;
  const int hoff = h * HDIM;

  // Load Q tile transposed: Qs[d][q]
  {
    const int d4 = (tid & 15) * 4;
    const int r0 = tid >> 4;
#pragma unroll
    for (int r = 0; r < 4; ++r) {
      const int q = r0 + 16 * r;
      const float4 t = *reinterpret_cast<const float4*>(
          &Q[(size_t)(q0 + q) * DMODEL + hoff + d4]);
      Qs[d4 + 0][q] = t.x;
      Qs[d4 + 1][q] = t.y;
      Qs[d4 + 2][q] = t.z;
      Qs[d4 + 3][q] = t.w;
    }
  }

  float m_i[4], l_i[4], o_acc[4][4];
#pragma unroll
  for (int i = 0; i < 4; ++i) {
    m_i[i] = -INFINITY;
    l_i[i] = 0.f;
#pragma unroll
    for (int j = 0; j < 4; ++j) o_acc[i][j] = 0.f;
  }

  const float scale = 0.125f;  // 1/sqrt(64)
  const int ntiles = q0 / 64 + 1;

  for (int t = 0; t < ntiles; ++t) {
    const int k0 = t * 64;

    __syncthreads();  // (a) previous PV reads done; safe to overwrite KPs/Vs

    // Load K tile (transposed -> [d][k]) and V tile (natural -> [k][d])
    {
      const int d4 = (tid & 15) * 4;
      const int r0 = tid >> 4;
#pragma unroll
      for (int r = 0; r < 4; ++r) {
        const int kk = r0 + 16 * r;
        const float4 tk = *reinterpret_cast<const float4*>(
            &K[(size_t)(k0 + kk) * DMODEL + hoff + d4]);
        KPs[d4 + 0][kk] = tk.x;
        KPs[d4 + 1][kk] = tk.y;
        KPs[d4 + 2][kk] = tk.z;
        KPs[d4 + 3][kk] = tk.w;
        const float4 tv = *reinterpret_cast<const float4*>(
            &V[(size_t)(k0 + kk) * DMODEL + hoff + d4]);
        *reinterpret_cast<float4*>(&Vs[kk][d4]) = tv;
      }
    }
    __syncthreads();  // (b) K/V tiles visible

    // S = Q K^T  (s[i][j]: q = q0+ty*4+i, k = k0+tx*4+j)
    float s[4][4] = {};
#pragma unroll 4
    for (int d = 0; d < 64; ++d) {
      const float4 a4 = *reinterpret_cast<const float4*>(&Qs[d][ty * 4]);
      const float4 b4 = *reinterpret_cast<const float4*>(&KPs[d][tx * 4]);
      const float av[4] = {a4.x, a4.y, a4.z, a4.w};
      const float bv[4] = {b4.x, b4.y, b4.z, b4.w};
#pragma unroll
      for (int i = 0; i < 4; ++i)
#pragma unroll
        for (int j = 0; j < 4; ++j)
          s[i][j] = fmaf(av[i], bv[j], s[i][j]);
    }

    // Scale + causal mask (only the diagonal tile has k > q cases)
    const bool diag = (t == ntiles - 1);
#pragma unroll
    for (int i = 0; i < 4; ++i)
#pragma unroll
      for (int j = 0; j < 4; ++j) {
        float v = s[i][j] * scale;
        if (diag) {
          const int qg = q0 + ty * 4 + i;
          const int kg = k0 + tx * 4 + j;
          if (kg > qg) v = -INFINITY;
        }
        s[i][j] = v;
      }

    // Online softmax (row reductions across the 16-lane tx group)
    float p[4][4];
    float alpha[4];
#pragma unroll
    for (int i = 0; i < 4; ++i) {
      float mt = fmaxf(fmaxf(s[i][0], s[i][1]), fmaxf(s[i][2], s[i][3]));
#pragma unroll
      for (int off = 1; off < 16; off <<= 1)
        mt = fmaxf(mt, __shfl_xor(mt, off));
      const float mnew = fmaxf(m_i[i], mt);
      alpha[i] = __expf(m_i[i] - mnew);  // exp(-inf - finite) = 0 on first tile
      float sum = 0.f;
#pragma unroll
      for (int j = 0; j < 4; ++j) {
        p[i][j] = __expf(s[i][j] - mnew);
        sum += p[i][j];
      }
#pragma unroll
      for (int off = 1; off < 16; off <<= 1)
        sum += __shfl_xor(sum, off);
      l_i[i] = l_i[i] * alpha[i] + sum;
      m_i[i] = mnew;
#pragma unroll
      for (int j = 0; j < 4; ++j) o_acc[i][j] *= alpha[i];
    }

    __syncthreads();  // (c) all K-tile reads done; KPs becomes the P buffer

    // Write P transposed: KPs[k][q]
#pragma unroll
    for (int j = 0; j < 4; ++j)
#pragma unroll
      for (int i = 0; i < 4; ++i)
        KPs[tx * 4 + j][ty * 4 + i] = p[i][j];

    __syncthreads();  // (d) P tile visible

    // O += P V  (o_acc[i][j]: q = ty*4+i, d = tx*4+j)
#pragma unroll 4
    for (int kk = 0; kk < 64; ++kk) {
      const float4 p4 = *reinterpret_cast<const float4*>(&KPs[kk][ty * 4]);
      const float4 v4 = *reinterpret_cast<const float4*>(&Vs[kk][tx * 4]);
      const float pv[4] = {p4.x, p4.y, p4.z, p4.w};
      const float vv[4] = {v4.x, v4.y, v4.z, v4.w};
#pragma unroll
      for (int i = 0; i < 4; ++i)
#pragma unroll
        for (int j = 0; j < 4; ++j)
          o_acc[i][j] = fmaf(pv[i], vv[j], o_acc[i][j]);
    }
  }

  // Epilogue: normalize and store ctx in [s][h*64+d] layout
#pragma unroll
  for (int i = 0; i < 4; ++i) {
    const float inv = 1.f / l_i[i];
    float4 o4;
    o4.x = o_acc[i][0] * inv;
    o4.y = o_acc[i][1] * inv;
    o4.z = o_acc[i][2] * inv;
    o4.w = o_acc[i][3] * inv;
    *reinterpret_cast<float4*>(
        &O[(size_t)(q0 + ty * 4 + i) * DMODEL + hoff + tx * 4]) = o4;
  }
}

// ---------------------------------------------------------------------------
extern "C" void kernel_launch(void* const* d_in, const int* in_sizes, int n_in,
                              void* d_out, int out_size, void* d_ws, size_t ws_size,
                              hipStream_t stream) {
  const float* x  = (const float*)d_in[0];
  const float* Wq = (const float*)d_in[1];
  const float* Wk = (const float*)d_in[2];
  const float* Wv = (const float*)d_in[3];
  const float* Wo = (const float*)d_in[4];
  const float* bo = (const float*)d_in[5];
  float* out = (float*)d_out;

  float* Qb  = (float*)d_ws;
  float* Kb  = Qb + (size_t)S_LEN * DMODEL;
  float* Vb  = Kb + (size_t)S_LEN * DMODEL;
  float* ctx = Vb + (size_t)S_LEN * DMODEL;

  const dim3 blk(256);
  const dim3 gemm_grid(DMODEL / 64, S_LEN / 64);  // (12, 64)

  gemm_abt<0><<<gemm_grid, blk, 0, stream>>>(x, Wq, nullptr, Qb, S_LEN, DMODEL, DMODEL);
  gemm_abt<0><<<gemm_grid, blk, 0, stream>>>(x, Wk, nullptr, Kb, S_LEN, DMODEL, DMODEL);
  gemm_abt<0><<<gemm_grid, blk, 0, stream>>>(x, Wv, nullptr, Vb, S_LEN, DMODEL, DMODEL);

  attn_fwd<<<dim3(S_LEN / 64, NHEAD), blk, 0, stream>>>(Qb, Kb, Vb, ctx);

  gemm_abt<1><<<gemm_grid, blk, 0, stream>>>(ctx, Wo, bo, out, S_LEN, DMODEL, DMODEL);
}

// Round 25
// 306.375 us; speedup vs baseline: 3.3419x; 3.3419x over previous
//
#include <hip/hip_runtime.h>
#include <math.h>

static constexpr int S_LEN  = 4096;
static constexpr int DMODEL = 768;
static constexpr int NHEAD  = 12;
static constexpr int HDIM   = 64;

typedef __attribute__((ext_vector_type(8))) short   bf16x8;
typedef __attribute__((ext_vector_type(4))) float   f32x4;
typedef __attribute__((ext_vector_type(8))) unsigned short us8;

__device__ __forceinline__ unsigned short f2b(float f) {
  union { float f; unsigned int u; } v; v.f = f;
  unsigned int u = v.u;
  return (unsigned short)((u + 0x7fffu + ((u >> 16) & 1u)) >> 16);  // RNE
}

// ---------------------------------------------------------------------------
// fp32 -> bf16 bulk convert (n multiple of 8, grid sized exactly)
// ---------------------------------------------------------------------------
__global__ __launch_bounds__(256)
void cvt_f2b_kern(const float* __restrict__ in, unsigned short* __restrict__ out, int n) {
  int i = (blockIdx.x * blockDim.x + threadIdx.x) * 8;
  if (i >= n) return;
  float4 a = *(const float4*)(in + i);
  float4 b = *(const float4*)(in + i + 4);
  ushort4 o0; o0.x = f2b(a.x); o0.y = f2b(a.y); o0.z = f2b(a.z); o0.w = f2b(a.w);
  ushort4 o1; o1.x = f2b(b.x); o1.y = f2b(b.y); o1.z = f2b(b.z); o1.w = f2b(b.w);
  *(ushort4*)(out + i)     = o0;
  *(ushort4*)(out + i + 4) = o1;
}

// ---------------------------------------------------------------------------
// bf16 transpose: in [S][D] -> out [D][S], 64x64 tiles via LDS.
// ---------------------------------------------------------------------------
__global__ __launch_bounds__(256)
void transpose_bf16(const unsigned short* __restrict__ in, unsigned short* __restrict__ out) {
  __shared__ __align__(16) unsigned short Ts[64][72];
  const int d0 = blockIdx.x * 64, s0 = blockIdx.y * 64;
  const int r = threadIdx.x >> 2, q = threadIdx.x & 3;
#pragma unroll
  for (int hh = 0; hh < 2; ++hh) {
    const int c8 = q + hh * 4;
    us8 v = *(const us8*)(in + (size_t)(s0 + r) * DMODEL + d0 + c8 * 8);
    *(us8*)(&Ts[r][c8 * 8]) = v;
  }
  __syncthreads();
#pragma unroll
  for (int hh = 0; hh < 2; ++hh) {
    const int sq = q + hh * 4;
    __align__(16) unsigned short tmp[8];
#pragma unroll
    for (int j = 0; j < 8; ++j) tmp[j] = Ts[sq * 8 + j][r];
    *(us8*)(out + (size_t)(d0 + r) * S_LEN + s0 + sq * 8) = *(us8*)tmp;
  }
}

// ---------------------------------------------------------------------------
// C[M,N] = A[M,K] @ B[N,K]^T, bf16 inputs via MFMA 16x16x32, fp32 accum.
// Block 64x64 (4 waves 2x2, wave tile 32x32 = 2x2 frags). Fragments loaded
// straight from global (B panel is L2-resident; K=768).
// OUT_MODE 0: bf16 out (scaled). OUT_MODE 1: fp32 out + bias.
// ---------------------------------------------------------------------------
template<int OUT_MODE>
__global__ __launch_bounds__(256)
void gemm_bf16(const unsigned short* __restrict__ A, const unsigned short* __restrict__ B,
               const float* __restrict__ bias, void* __restrict__ Cout,
               int M, int N, int K, float scale) {
  const int l  = threadIdx.x & 63;
  const int w  = threadIdx.x >> 6;
  const int wm = (w >> 1) * 32, wn = (w & 1) * 32;
  const int m0 = blockIdx.y * 64 + wm;
  const int n0 = blockIdx.x * 64 + wn;
  const int lr = l & 15, lk = (l >> 4) * 8;

  f32x4 acc[2][2] = {};
  const unsigned short* Ap = A + (size_t)(m0 + lr) * K + lk;
  const unsigned short* Bp = B + (size_t)(n0 + lr) * K + lk;
  const size_t a16 = (size_t)16 * K;

#pragma unroll 4
  for (int k0 = 0; k0 < K; k0 += 32) {
    bf16x8 a0 = *(const bf16x8*)(Ap + k0);
    bf16x8 a1 = *(const bf16x8*)(Ap + a16 + k0);
    bf16x8 b0 = *(const bf16x8*)(Bp + k0);
    bf16x8 b1 = *(const bf16x8*)(Bp + a16 + k0);
    acc[0][0] = __builtin_amdgcn_mfma_f32_16x16x32_bf16(a0, b0, acc[0][0], 0, 0, 0);
    acc[0][1] = __builtin_amdgcn_mfma_f32_16x16x32_bf16(a0, b1, acc[0][1], 0, 0, 0);
    acc[1][0] = __builtin_amdgcn_mfma_f32_16x16x32_bf16(a1, b0, acc[1][0], 0, 0, 0);
    acc[1][1] = __builtin_amdgcn_mfma_f32_16x16x32_bf16(a1, b1, acc[1][1], 0, 0, 0);
  }

  const int orow = (l >> 4) * 4;
#pragma unroll
  for (int mi = 0; mi < 2; ++mi)
#pragma unroll
    for (int ni = 0; ni < 2; ++ni) {
      const int col = n0 + ni * 16 + lr;
      float bb = (OUT_MODE == 1) ? bias[col] : 0.f;
#pragma unroll
      for (int r = 0; r < 4; ++r) {
        const int row = m0 + mi * 16 + orow + r;
        float v = acc[mi][ni][r] * scale;
        if (OUT_MODE == 0)
          ((unsigned short*)Cout)[(size_t)row * N + col] = f2b(v);
        else
          ((float*)Cout)[(size_t)row * N + col] = v + bb;
      }
    }
}

// ---------------------------------------------------------------------------
// Flash-style causal attention, bf16 MFMA + fp32 online softmax.
// Grid: 768 blocks (LPT order: heaviest q-tiles first). Block = 4 waves,
// one (q-tile, head). Q frags in registers (scale pre-folded into Q).
// K tile LDS [kv][d] XOR-swizzled; V tile from pre-transposed Vt as [d][kv]
// XOR-swizzled; P re-layout through per-wave LDS (no barrier needed).
// ---------------------------------------------------------------------------
__global__ __launch_bounds__(256, 3)
void attn_fwd_mfma(const unsigned short* __restrict__ Q, const unsigned short* __restrict__ K,
                   const unsigned short* __restrict__ Vt, unsigned short* __restrict__ O) {
  __shared__ __align__(16) unsigned short Ks[64 * 64];
  __shared__ __align__(16) unsigned short Vs[64 * 64];
  __shared__ __align__(16) unsigned short Ps[4][16 * 64];

  const int item = blockIdx.x;
  const int qt = 63 - item / NHEAD;   // LPT: longest blocks dispatch first
  const int h  = item % NHEAD;
  const int q0 = qt * 64;
  const int tid = threadIdx.x;
  const int w = tid >> 6, l = tid & 63;
  const int lr = l & 15, lg = l >> 4;
  const int sr = tid >> 2, sq = tid & 3;   // staging: row, qword base

  // Q fragments (held in registers for the whole kernel)
  bf16x8 qf[2];
#pragma unroll
  for (int kc = 0; kc < 2; ++kc)
    qf[kc] = *(const bf16x8*)(Q + (size_t)(q0 + w * 16 + lr) * DMODEL + h * HDIM + kc * 32 + lg * 8);

  f32x4 o_acc[4] = {};
  float m_i[4], l_i[4];
#pragma unroll
  for (int r = 0; r < 4; ++r) { m_i[r] = -1e30f; l_i[r] = 0.f; }

  for (int t = 0; t <= qt; ++t) {
    const int k0 = t * 64;

    // ---- stage K tile [kv][d] and V tile [d][kv], both XOR-swizzled ----
#pragma unroll
    for (int p = 0; p < 2; ++p) {
      const int qw = sq + p * 4;
      us8 kv8 = *(const us8*)(K  + (size_t)(k0 + sr) * DMODEL + h * HDIM + qw * 8);
      us8 vv8 = *(const us8*)(Vt + (size_t)(h * HDIM + sr) * S_LEN + k0 + qw * 8);
      const int sw = (qw * 8) ^ ((sr & 7) * 8);
      *(us8*)(&Ks[sr * 64 + sw]) = kv8;
      *(us8*)(&Vs[sr * 64 + sw]) = vv8;
    }
    __syncthreads();

    // ---- S = Q K^T (scale pre-folded into Q) ----
    f32x4 sacc[4] = {};
#pragma unroll
    for (int kc = 0; kc < 2; ++kc)
#pragma unroll
      for (int cb = 0; cb < 4; ++cb) {
        const int kv = cb * 16 + lr;
        bf16x8 kf = *(const bf16x8*)(&Ks[kv * 64 + ((kc * 32 + lg * 8) ^ ((kv & 7) * 8))]);
        sacc[cb] = __builtin_amdgcn_mfma_f32_16x16x32_bf16(qf[kc], kf, sacc[cb], 0, 0, 0);
      }

    // ---- online softmax (fp32, per q-row; rows live in 16-lane groups) ----
    const bool diag = (t == qt);
    float p[4][4];
#pragma unroll
    for (int r = 0; r < 4; ++r) {
      const int qg = q0 + w * 16 + lg * 4 + r;
      float sv[4];
#pragma unroll
      for (int cb = 0; cb < 4; ++cb) {
        float v = sacc[cb][r];
        if (diag && (k0 + cb * 16 + lr) > qg) v = -1e30f;
        sv[cb] = v;
      }
      float mt = fmaxf(fmaxf(sv[0], sv[1]), fmaxf(sv[2], sv[3]));
      mt = fmaxf(mt, __shfl_xor(mt, 1));
      mt = fmaxf(mt, __shfl_xor(mt, 2));
      mt = fmaxf(mt, __shfl_xor(mt, 4));
      mt = fmaxf(mt, __shfl_xor(mt, 8));
      const float mnew = fmaxf(m_i[r], mt);
      const float alpha = __expf(m_i[r] - mnew);
      m_i[r] = mnew;
      float rs = 0.f;
#pragma unroll
      for (int cb = 0; cb < 4; ++cb) { p[r][cb] = __expf(sv[cb] - mnew); rs += p[r][cb]; }
      rs += __shfl_xor(rs, 1); rs += __shfl_xor(rs, 2);
      rs += __shfl_xor(rs, 4); rs += __shfl_xor(rs, 8);
      l_i[r] = l_i[r] * alpha + rs;
#pragma unroll
      for (int db = 0; db < 4; ++db) o_acc[db][r] *= alpha;
    }

    // ---- P -> bf16, per-wave LDS re-layout (acc layout -> A-frag layout) ----
#pragma unroll
    for (int r = 0; r < 4; ++r) {
      const int qloc = lg * 4 + r;
#pragma unroll
      for (int cb = 0; cb < 4; ++cb) {
        const int kv = cb * 16 + lr;
        Ps[w][qloc * 64 + (kv ^ ((qloc & 7) * 8))] = f2b(p[r][cb]);
      }
    }

    // ---- O += P V ----
#pragma unroll
    for (int kc = 0; kc < 2; ++kc) {
      bf16x8 pf = *(const bf16x8*)(&Ps[w][lr * 64 + ((kc * 32 + lg * 8) ^ ((lr & 7) * 8))]);
#pragma unroll
      for (int db = 0; db < 4; ++db) {
        const int d = db * 16 + lr;
        bf16x8 vf = *(const bf16x8*)(&Vs[d * 64 + ((kc * 32 + lg * 8) ^ ((d & 7) * 8))]);
        o_acc[db] = __builtin_amdgcn_mfma_f32_16x16x32_bf16(pf, vf, o_acc[db], 0, 0, 0);
      }
    }
    __syncthreads();
  }

  // ---- epilogue: normalize, store ctx (bf16) ----
#pragma unroll
  for (int r = 0; r < 4; ++r) {
    const float inv = 1.f / l_i[r];
    const int row = q0 + w * 16 + lg * 4 + r;
#pragma unroll
    for (int db = 0; db < 4; ++db)
      O[(size_t)row * DMODEL + h * HDIM + db * 16 + lr] = f2b(o_acc[db][r] * inv);
  }
}

// ---------------------------------------------------------------------------
extern "C" void kernel_launch(void* const* d_in, const int* in_sizes, int n_in,
                              void* d_out, int out_size, void* d_ws, size_t ws_size,
                              hipStream_t stream) {
  const float* x  = (const float*)d_in[0];
  const float* Wq = (const float*)d_in[1];
  const float* Wk = (const float*)d_in[2];
  const float* Wv = (const float*)d_in[3];
  const float* Wo = (const float*)d_in[4];
  const float* bo = (const float*)d_in[5];
  float* out = (float*)d_out;

  const size_t SD = (size_t)S_LEN * DMODEL;   // 3,145,728
  const size_t DD = (size_t)DMODEL * DMODEL;  //   589,824

  unsigned short* xh   = (unsigned short*)d_ws;
  unsigned short* Wqh  = xh   + SD;
  unsigned short* Wkh  = Wqh  + DD;
  unsigned short* Wvh  = Wkh  + DD;
  unsigned short* Woh  = Wvh  + DD;
  unsigned short* Qh   = Woh  + DD;
  unsigned short* Kh   = Qh   + SD;
  unsigned short* Vh   = Kh   + SD;
  unsigned short* Vth  = Vh   + SD;
  unsigned short* ctxh = Vth  + SD;

  const dim3 blk(256);

  cvt_f2b_kern<<<dim3((int)(SD / 8 / 256)), blk, 0, stream>>>(x,  xh,  (int)SD);
  cvt_f2b_kern<<<dim3((int)(DD / 8 / 256)), blk, 0, stream>>>(Wq, Wqh, (int)DD);
  cvt_f2b_kern<<<dim3((int)(DD / 8 / 256)), blk, 0, stream>>>(Wk, Wkh, (int)DD);
  cvt_f2b_kern<<<dim3((int)(DD / 8 / 256)), blk, 0, stream>>>(Wv, Wvh, (int)DD);
  cvt_f2b_kern<<<dim3((int)(DD / 8 / 256)), blk, 0, stream>>>(Wo, Woh, (int)DD);

  const dim3 gg(DMODEL / 64, S_LEN / 64);  // (12, 64)
  gemm_bf16<0><<<gg, blk, 0, stream>>>(xh, Wqh, nullptr, Qh, S_LEN, DMODEL, DMODEL, 0.125f);
  gemm_bf16<0><<<gg, blk, 0, stream>>>(xh, Wkh, nullptr, Kh, S_LEN, DMODEL, DMODEL, 1.0f);
  gemm_bf16<0><<<gg, blk, 0, stream>>>(xh, Wvh, nullptr, Vh, S_LEN, DMODEL, DMODEL, 1.0f);

  transpose_bf16<<<dim3(DMODEL / 64, S_LEN / 64), blk, 0, stream>>>(Vh, Vth);

  attn_fwd_mfma<<<dim3(S_LEN / 64 * NHEAD), blk, 0, stream>>>(Qh, Kh, Vth, ctxh);

  gemm_bf16<1><<<gg, blk, 0, stream>>>(ctxh, Woh, bo, out, S_LEN, DMODEL, DMODEL, 1.0f);
}

// Round 26
// 246.460 us; speedup vs baseline: 4.1543x; 1.2431x over previous
//
#include <hip/hip_runtime.h>
#include <math.h>

static constexpr int S_LEN  = 4096;
static constexpr int DMODEL = 768;
static constexpr int NHEAD  = 12;
static constexpr int HDIM   = 64;

typedef __attribute__((ext_vector_type(8))) short   bf16x8;
typedef __attribute__((ext_vector_type(4))) float   f32x4;
typedef __attribute__((ext_vector_type(8))) unsigned short us8;

__device__ __forceinline__ unsigned short f2b(float f) {
  union { float f; unsigned int u; } v; v.f = f;
  unsigned int u = v.u;
  return (unsigned short)((u + 0x7fffu + ((u >> 16) & 1u)) >> 16);  // RNE
}

// ---------------------------------------------------------------------------
// fp32 -> bf16 bulk convert (n multiple of 8, grid sized exactly)
// ---------------------------------------------------------------------------
__global__ __launch_bounds__(256)
void cvt_f2b_kern(const float* __restrict__ in, unsigned short* __restrict__ out, int n) {
  int i = (blockIdx.x * blockDim.x + threadIdx.x) * 8;
  if (i >= n) return;
  float4 a = *(const float4*)(in + i);
  float4 b = *(const float4*)(in + i + 4);
  ushort4 o0; o0.x = f2b(a.x); o0.y = f2b(a.y); o0.z = f2b(a.z); o0.w = f2b(a.w);
  ushort4 o1; o1.x = f2b(b.x); o1.y = f2b(b.y); o1.z = f2b(b.z); o1.w = f2b(b.w);
  *(ushort4*)(out + i)     = o0;
  *(ushort4*)(out + i + 4) = o1;
}

// ---------------------------------------------------------------------------
// bf16 transpose: in [S][D] -> out [D][S], 64x64 tiles via LDS.
// ---------------------------------------------------------------------------
__global__ __launch_bounds__(256)
void transpose_bf16(const unsigned short* __restrict__ in, unsigned short* __restrict__ out) {
  __shared__ __align__(16) unsigned short Ts[64][72];
  const int d0 = blockIdx.x * 64, s0 = blockIdx.y * 64;
  const int r = threadIdx.x >> 2, q = threadIdx.x & 3;
#pragma unroll
  for (int hh = 0; hh < 2; ++hh) {
    const int c8 = q + hh * 4;
    us8 v = *(const us8*)(in + (size_t)(s0 + r) * DMODEL + d0 + c8 * 8);
    *(us8*)(&Ts[r][c8 * 8]) = v;
  }
  __syncthreads();
#pragma unroll
  for (int hh = 0; hh < 2; ++hh) {
    const int sq = q + hh * 4;
    __align__(16) unsigned short tmp[8];
#pragma unroll
    for (int j = 0; j < 8; ++j) tmp[j] = Ts[sq * 8 + j][r];
    *(us8*)(out + (size_t)(d0 + r) * S_LEN + s0 + sq * 8) = *(us8*)tmp;
  }
}

// ---------------------------------------------------------------------------
// C[M,N] = A[M,K] @ B[N,K]^T, bf16 inputs via MFMA 16x16x32, fp32 accum.
// (unchanged from R25 measured build)
// ---------------------------------------------------------------------------
template<int OUT_MODE>
__global__ __launch_bounds__(256)
void gemm_bf16(const unsigned short* __restrict__ A, const unsigned short* __restrict__ B,
               const float* __restrict__ bias, void* __restrict__ Cout,
               int M, int N, int K, float scale) {
  const int l  = threadIdx.x & 63;
  const int w  = threadIdx.x >> 6;
  const int wm = (w >> 1) * 32, wn = (w & 1) * 32;
  const int m0 = blockIdx.y * 64 + wm;
  const int n0 = blockIdx.x * 64 + wn;
  const int lr = l & 15, lk = (l >> 4) * 8;

  f32x4 acc[2][2] = {};
  const unsigned short* Ap = A + (size_t)(m0 + lr) * K + lk;
  const unsigned short* Bp = B + (size_t)(n0 + lr) * K + lk;
  const size_t a16 = (size_t)16 * K;

#pragma unroll 4
  for (int k0 = 0; k0 < K; k0 += 32) {
    bf16x8 a0 = *(const bf16x8*)(Ap + k0);
    bf16x8 a1 = *(const bf16x8*)(Ap + a16 + k0);
    bf16x8 b0 = *(const bf16x8*)(Bp + k0);
    bf16x8 b1 = *(const bf16x8*)(Bp + a16 + k0);
    acc[0][0] = __builtin_amdgcn_mfma_f32_16x16x32_bf16(a0, b0, acc[0][0], 0, 0, 0);
    acc[0][1] = __builtin_amdgcn_mfma_f32_16x16x32_bf16(a0, b1, acc[0][1], 0, 0, 0);
    acc[1][0] = __builtin_amdgcn_mfma_f32_16x16x32_bf16(a1, b0, acc[1][0], 0, 0, 0);
    acc[1][1] = __builtin_amdgcn_mfma_f32_16x16x32_bf16(a1, b1, acc[1][1], 0, 0, 0);
  }

  const int orow = (l >> 4) * 4;
#pragma unroll
  for (int mi = 0; mi < 2; ++mi)
#pragma unroll
    for (int ni = 0; ni < 2; ++ni) {
      const int col = n0 + ni * 16 + lr;
      float bb = (OUT_MODE == 1) ? bias[col] : 0.f;
#pragma unroll
      for (int r = 0; r < 4; ++r) {
        const int row = m0 + mi * 16 + orow + r;
        float v = acc[mi][ni][r] * scale;
        if (OUT_MODE == 0)
          ((unsigned short*)Cout)[(size_t)row * N + col] = f2b(v);
        else
          ((float*)Cout)[(size_t)row * N + col] = v + bb;
      }
    }
}

// ---------------------------------------------------------------------------
// Flash-style causal attention, bf16 MFMA + fp32 online softmax.
// KVBLK=128 (two 64-halves per iteration, ONE softmax update per 128 kv) +
// register prefetch of the next tile (loads issued before QK^T, LDS write
// after the post-compute barrier -> latency hidden under compute).
// Causal mask applied unconditionally (covers partial last tiles).
// LDS 48 KB -> 3 blocks/CU.
// ---------------------------------------------------------------------------
__global__ __launch_bounds__(256, 3)
void attn_fwd_mfma(const unsigned short* __restrict__ Q, const unsigned short* __restrict__ K,
                   const unsigned short* __restrict__ Vt, unsigned short* __restrict__ O) {
  __shared__ __align__(16) unsigned short Ks[2][64 * 64];
  __shared__ __align__(16) unsigned short Vs[2][64 * 64];
  __shared__ __align__(16) unsigned short Ps[4][2 * 16 * 64];

  const int item = blockIdx.x;
  const int qt = 63 - item / NHEAD;   // LPT: longest blocks dispatch first
  const int h  = item % NHEAD;
  const int q0 = qt * 64;
  const int tid = threadIdx.x;
  const int w = tid >> 6, l = tid & 63;
  const int lr = l & 15, lg = l >> 4;
  const int sr = tid >> 2, sq = tid & 3;   // staging: row, qword base

  // Q fragments (held in registers; scale pre-folded into Q)
  bf16x8 qf[2];
#pragma unroll
  for (int kc = 0; kc < 2; ++kc)
    qf[kc] = *(const bf16x8*)(Q + (size_t)(q0 + w * 16 + lr) * DMODEL + h * HDIM + kc * 32 + lg * 8);

  f32x4 o_acc[4] = {};
  float m_i[4], l_i[4];
#pragma unroll
  for (int r = 0; r < 4; ++r) { m_i[r] = -1e30f; l_i[r] = 0.f; }

  const int nt2 = (qt + 2) >> 1;   // ceil((qt+1)/2) 128-wide iterations

  us8 kreg[2][2], vreg[2][2];

  // ---- prologue: stage tile 0 (both halves) ----
#pragma unroll
  for (int hh = 0; hh < 2; ++hh)
#pragma unroll
    for (int p = 0; p < 2; ++p) {
      const int qw = sq + p * 4;
      kreg[hh][p] = *(const us8*)(K  + (size_t)(hh * 64 + sr) * DMODEL + h * HDIM + qw * 8);
      vreg[hh][p] = *(const us8*)(Vt + (size_t)(h * HDIM + sr) * S_LEN + hh * 64 + qw * 8);
    }
#pragma unroll
  for (int hh = 0; hh < 2; ++hh)
#pragma unroll
    for (int p = 0; p < 2; ++p) {
      const int qw = sq + p * 4;
      const int sw = (qw * 8) ^ ((sr & 7) * 8);
      *(us8*)(&Ks[hh][sr * 64 + sw]) = kreg[hh][p];
      *(us8*)(&Vs[hh][sr * 64 + sw]) = vreg[hh][p];
    }
  __syncthreads();

  for (int t = 0; t < nt2; ++t) {
    const int k0 = t * 128;
    const bool more = (t + 1 < nt2);

    // ---- prefetch next 128-kv tile into registers (latency hides under compute) ----
    if (more) {
      const int k0n = k0 + 128;
#pragma unroll
      for (int hh = 0; hh < 2; ++hh)
#pragma unroll
        for (int p = 0; p < 2; ++p) {
          const int qw = sq + p * 4;
          kreg[hh][p] = *(const us8*)(K  + (size_t)(k0n + hh * 64 + sr) * DMODEL + h * HDIM + qw * 8);
          vreg[hh][p] = *(const us8*)(Vt + (size_t)(h * HDIM + sr) * S_LEN + k0n + hh * 64 + qw * 8);
        }
    }

    // ---- S = Q K^T over 128 kv (16 MFMA) ----
    f32x4 sacc[2][4] = {};
#pragma unroll
    for (int hh = 0; hh < 2; ++hh)
#pragma unroll
      for (int kc = 0; kc < 2; ++kc)
#pragma unroll
        for (int cb = 0; cb < 4; ++cb) {
          const int kv = cb * 16 + lr;
          bf16x8 kf = *(const bf16x8*)(&Ks[hh][kv * 64 + ((kc * 32 + lg * 8) ^ ((kv & 7) * 8))]);
          sacc[hh][cb] = __builtin_amdgcn_mfma_f32_16x16x32_bf16(qf[kc], kf, sacc[hh][cb], 0, 0, 0);
        }

    // ---- online softmax: ONE update per 128 kv (8 elems/row) ----
    float p[4][8];
#pragma unroll
    for (int r = 0; r < 4; ++r) {
      const int qg = q0 + w * 16 + lg * 4 + r;
      float sv[8];
#pragma unroll
      for (int hh = 0; hh < 2; ++hh)
#pragma unroll
        for (int cb = 0; cb < 4; ++cb) {
          const int kg = k0 + hh * 64 + cb * 16 + lr;
          float v = sacc[hh][cb][r];
          sv[hh * 4 + cb] = (kg > qg) ? -1e30f : v;
        }
      float mt = fmaxf(fmaxf(fmaxf(sv[0], sv[1]), fmaxf(sv[2], sv[3])),
                       fmaxf(fmaxf(sv[4], sv[5]), fmaxf(sv[6], sv[7])));
      mt = fmaxf(mt, __shfl_xor(mt, 1));
      mt = fmaxf(mt, __shfl_xor(mt, 2));
      mt = fmaxf(mt, __shfl_xor(mt, 4));
      mt = fmaxf(mt, __shfl_xor(mt, 8));
      const float mnew = fmaxf(m_i[r], mt);
      const float alpha = __expf(m_i[r] - mnew);
      m_i[r] = mnew;
      float rs = 0.f;
#pragma unroll
      for (int e = 0; e < 8; ++e) { p[r][e] = __expf(sv[e] - mnew); rs += p[r][e]; }
      rs += __shfl_xor(rs, 1); rs += __shfl_xor(rs, 2);
      rs += __shfl_xor(rs, 4); rs += __shfl_xor(rs, 8);
      l_i[r] = l_i[r] * alpha + rs;
#pragma unroll
      for (int db = 0; db < 4; ++db) o_acc[db][r] *= alpha;
    }

    // ---- P -> bf16, per-wave LDS re-layout (both halves) ----
#pragma unroll
    for (int r = 0; r < 4; ++r) {
      const int qloc = lg * 4 + r;
#pragma unroll
      for (int hh = 0; hh < 2; ++hh)
#pragma unroll
        for (int cb = 0; cb < 4; ++cb) {
          const int kvl = cb * 16 + lr;
          Ps[w][hh * 1024 + qloc * 64 + (kvl ^ ((qloc & 7) * 8))] = f2b(p[r][hh * 4 + cb]);
        }
    }

    // ---- O += P V over 128 kv (16 MFMA) ----
#pragma unroll
    for (int hh = 0; hh < 2; ++hh)
#pragma unroll
      for (int kc = 0; kc < 2; ++kc) {
        bf16x8 pf = *(const bf16x8*)(&Ps[w][hh * 1024 + lr * 64 + ((kc * 32 + lg * 8) ^ ((lr & 7) * 8))]);
#pragma unroll
        for (int db = 0; db < 4; ++db) {
          const int d = db * 16 + lr;
          bf16x8 vf = *(const bf16x8*)(&Vs[hh][d * 64 + ((kc * 32 + lg * 8) ^ ((d & 7) * 8))]);
          o_acc[db] = __builtin_amdgcn_mfma_f32_16x16x32_bf16(pf, vf, o_acc[db], 0, 0, 0);
        }
      }

    __syncthreads();   // all reads of Ks/Vs done
    if (more) {
#pragma unroll
      for (int hh = 0; hh < 2; ++hh)
#pragma unroll
        for (int p = 0; p < 2; ++p) {
          const int qw = sq + p * 4;
          const int sw = (qw * 8) ^ ((sr & 7) * 8);
          *(us8*)(&Ks[hh][sr * 64 + sw]) = kreg[hh][p];
          *(us8*)(&Vs[hh][sr * 64 + sw]) = vreg[hh][p];
        }
      __syncthreads();   // next tile visible
    }
  }

  // ---- epilogue: normalize, store ctx (bf16) ----
#pragma unroll
  for (int r = 0; r < 4; ++r) {
    const float inv = 1.f / l_i[r];
    const int row = q0 + w * 16 + lg * 4 + r;
#pragma unroll
    for (int db = 0; db < 4; ++db)
      O[(size_t)row * DMODEL + h * HDIM + db * 16 + lr] = f2b(o_acc[db][r] * inv);
  }
}

// ---------------------------------------------------------------------------
extern "C" void kernel_launch(void* const* d_in, const int* in_sizes, int n_in,
                              void* d_out, int out_size, void* d_ws, size_t ws_size,
                              hipStream_t stream) {
  const float* x  = (const float*)d_in[0];
  const float* Wq = (const float*)d_in[1];
  const float* Wk = (const float*)d_in[2];
  const float* Wv = (const float*)d_in[3];
  const float* Wo = (const float*)d_in[4];
  const float* bo = (const float*)d_in[5];
  float* out = (float*)d_out;

  const size_t SD = (size_t)S_LEN * DMODEL;   // 3,145,728
  const size_t DD = (size_t)DMODEL * DMODEL;  //   589,824

  unsigned short* xh   = (unsigned short*)d_ws;
  unsigned short* Wqh  = xh   + SD;
  unsigned short* Wkh  = Wqh  + DD;
  unsigned short* Wvh  = Wkh  + DD;
  unsigned short* Woh  = Wvh  + DD;
  unsigned short* Qh   = Woh  + DD;
  unsigned short* Kh   = Qh   + SD;
  unsigned short* Vh   = Kh   + SD;
  unsigned short* Vth  = Vh   + SD;
  unsigned short* ctxh = Vth  + SD;

  const dim3 blk(256);

  cvt_f2b_kern<<<dim3((int)(SD / 8 / 256)), blk, 0, stream>>>(x,  xh,  (int)SD);
  cvt_f2b_kern<<<dim3((int)(DD / 8 / 256)), blk, 0, stream>>>(Wq, Wqh, (int)DD);
  cvt_f2b_kern<<<dim3((int)(DD / 8 / 256)), blk, 0, stream>>>(Wk, Wkh, (int)DD);
  cvt_f2b_kern<<<dim3((int)(DD / 8 / 256)), blk, 0, stream>>>(Wv, Wvh, (int)DD);
  cvt_f2b_kern<<<dim3((int)(DD / 8 / 256)), blk, 0, stream>>>(Wo, Woh, (int)DD);

  const dim3 gg(DMODEL / 64, S_LEN / 64);  // (12, 64)
  gemm_bf16<0><<<gg, blk, 0, stream>>>(xh, Wqh, nullptr, Qh, S_LEN, DMODEL, DMODEL, 0.125f);
  gemm_bf16<0><<<gg, blk, 0, stream>>>(xh, Wkh, nullptr, Kh, S_LEN, DMODEL, DMODEL, 1.0f);
  gemm_bf16<0><<<gg, blk, 0, stream>>>(xh, Wvh, nullptr, Vh, S_LEN, DMODEL, DMODEL, 1.0f);

  transpose_bf16<<<dim3(DMODEL / 64, S_LEN / 64), blk, 0, stream>>>(Vh, Vth);

  attn_fwd_mfma<<<dim3(S_LEN / 64 * NHEAD), blk, 0, stream>>>(Qh, Kh, Vth, ctxh);

  gemm_bf16<1><<<gg, blk, 0, stream>>>(ctxh, Woh, bo, out, S_LEN, DMODEL, DMODEL, 1.0f);
}

// Round 27
// 231.258 us; speedup vs baseline: 4.4274x; 1.0657x over previous
//
#include <hip/hip_runtime.h>
#include <math.h>

static constexpr int S_LEN  = 4096;
static constexpr int DMODEL = 768;
static constexpr int NHEAD  = 12;
static constexpr int HDIM   = 64;

typedef __attribute__((ext_vector_type(8))) short   bf16x8;
typedef __attribute__((ext_vector_type(4))) float   f32x4;
typedef __attribute__((ext_vector_type(8))) unsigned short us8;

__device__ __forceinline__ unsigned short f2b(float f) {
  union { float f; unsigned int u; } v; v.f = f;
  unsigned int u = v.u;
  return (unsigned short)((u + 0x7fffu + ((u >> 16) & 1u)) >> 16);  // RNE
}

// DPP butterfly reduction within 16-lane groups (pure VALU; replaces
// ds-pipe shfl chains). quad_perm xor1/xor2, then row_ror:4/8 which are
// equivalent to xor4/xor8 once quads/octets are uniform.
__device__ __forceinline__ float dpp_max16(float x) {
  float y;
  y = __int_as_float(__builtin_amdgcn_mov_dpp(__float_as_int(x), 0xB1, 0xf, 0xf, true)); x = fmaxf(x, y);
  y = __int_as_float(__builtin_amdgcn_mov_dpp(__float_as_int(x), 0x4E, 0xf, 0xf, true)); x = fmaxf(x, y);
  y = __int_as_float(__builtin_amdgcn_mov_dpp(__float_as_int(x), 0x124, 0xf, 0xf, true)); x = fmaxf(x, y);
  y = __int_as_float(__builtin_amdgcn_mov_dpp(__float_as_int(x), 0x128, 0xf, 0xf, true)); x = fmaxf(x, y);
  return x;
}
__device__ __forceinline__ float dpp_sum16(float x) {
  float y;
  y = __int_as_float(__builtin_amdgcn_mov_dpp(__float_as_int(x), 0xB1, 0xf, 0xf, true)); x += y;
  y = __int_as_float(__builtin_amdgcn_mov_dpp(__float_as_int(x), 0x4E, 0xf, 0xf, true)); x += y;
  y = __int_as_float(__builtin_amdgcn_mov_dpp(__float_as_int(x), 0x124, 0xf, 0xf, true)); x += y;
  y = __int_as_float(__builtin_amdgcn_mov_dpp(__float_as_int(x), 0x128, 0xf, 0xf, true)); x += y;
  return x;
}

// ---------------------------------------------------------------------------
// fp32 -> bf16 bulk convert (n multiple of 8, grid sized exactly)
// ---------------------------------------------------------------------------
__global__ __launch_bounds__(256)
void cvt_f2b_kern(const float* __restrict__ in, unsigned short* __restrict__ out, int n) {
  int i = (blockIdx.x * blockDim.x + threadIdx.x) * 8;
  if (i >= n) return;
  float4 a = *(const float4*)(in + i);
  float4 b = *(const float4*)(in + i + 4);
  ushort4 o0; o0.x = f2b(a.x); o0.y = f2b(a.y); o0.z = f2b(a.z); o0.w = f2b(a.w);
  ushort4 o1; o1.x = f2b(b.x); o1.y = f2b(b.y); o1.z = f2b(b.z); o1.w = f2b(b.w);
  *(ushort4*)(out + i)     = o0;
  *(ushort4*)(out + i + 4) = o1;
}

// 4 weight matrices in one launch (blockIdx.y selects the matrix)
__global__ __launch_bounds__(256)
void cvt_f2b4_kern(const float* __restrict__ s0, const float* __restrict__ s1,
                   const float* __restrict__ s2, const float* __restrict__ s3,
                   unsigned short* __restrict__ d0, unsigned short* __restrict__ d1,
                   unsigned short* __restrict__ d2, unsigned short* __restrict__ d3,
                   int n) {
  const float* s; unsigned short* d;
  switch (blockIdx.y) {
    case 0: s = s0; d = d0; break;
    case 1: s = s1; d = d1; break;
    case 2: s = s2; d = d2; break;
    default: s = s3; d = d3; break;
  }
  int i = (blockIdx.x * blockDim.x + threadIdx.x) * 8;
  if (i >= n) return;
  float4 a = *(const float4*)(s + i);
  float4 b = *(const float4*)(s + i + 4);
  ushort4 o0; o0.x = f2b(a.x); o0.y = f2b(a.y); o0.z = f2b(a.z); o0.w = f2b(a.w);
  ushort4 o1; o1.x = f2b(b.x); o1.y = f2b(b.y); o1.z = f2b(b.z); o1.w = f2b(b.w);
  *(ushort4*)(d + i)     = o0;
  *(ushort4*)(d + i + 4) = o1;
}

// ---------------------------------------------------------------------------
// bf16 transpose: in [S][D] -> out [D][S], 64x64 tiles via LDS.
// ---------------------------------------------------------------------------
__global__ __launch_bounds__(256)
void transpose_bf16(const unsigned short* __restrict__ in, unsigned short* __restrict__ out) {
  __shared__ __align__(16) unsigned short Ts[64][72];
  const int d0 = blockIdx.x * 64, s0 = blockIdx.y * 64;
  const int r = threadIdx.x >> 2, q = threadIdx.x & 3;
#pragma unroll
  for (int hh = 0; hh < 2; ++hh) {
    const int c8 = q + hh * 4;
    us8 v = *(const us8*)(in + (size_t)(s0 + r) * DMODEL + d0 + c8 * 8);
    *(us8*)(&Ts[r][c8 * 8]) = v;
  }
  __syncthreads();
#pragma unroll
  for (int hh = 0; hh < 2; ++hh) {
    const int sq = q + hh * 4;
    __align__(16) unsigned short tmp[8];
#pragma unroll
    for (int j = 0; j < 8; ++j) tmp[j] = Ts[sq * 8 + j][r];
    *(us8*)(out + (size_t)(d0 + r) * S_LEN + s0 + sq * 8) = *(us8*)tmp;
  }
}

// ---------------------------------------------------------------------------
// C[M,N] = A[M,K] @ B[N,K]^T, bf16 MFMA 16x16x32, fp32 accum.
// K-loop software pipeline: next k-step's 4 fragments prefetched into
// registers while the current 4 MFMAs issue (removes load->MFMA dep).
// ---------------------------------------------------------------------------
template<int OUT_MODE>
__global__ __launch_bounds__(256)
void gemm_bf16(const unsigned short* __restrict__ A, const unsigned short* __restrict__ B,
               const float* __restrict__ bias, void* __restrict__ Cout,
               int M, int N, int K, float scale) {
  const int l  = threadIdx.x & 63;
  const int w  = threadIdx.x >> 6;
  const int wm = (w >> 1) * 32, wn = (w & 1) * 32;
  const int m0 = blockIdx.y * 64 + wm;
  const int n0 = blockIdx.x * 64 + wn;
  const int lr = l & 15, lk = (l >> 4) * 8;

  f32x4 acc[2][2] = {};
  const unsigned short* Ap = A + (size_t)(m0 + lr) * K + lk;
  const unsigned short* Bp = B + (size_t)(n0 + lr) * K + lk;
  const size_t a16 = (size_t)16 * K;

  bf16x8 a0 = *(const bf16x8*)(Ap);
  bf16x8 a1 = *(const bf16x8*)(Ap + a16);
  bf16x8 b0 = *(const bf16x8*)(Bp);
  bf16x8 b1 = *(const bf16x8*)(Bp + a16);

#pragma unroll 2
  for (int k0 = 0; k0 < K - 32; k0 += 32) {
    const int kn = k0 + 32;
    bf16x8 a0n = *(const bf16x8*)(Ap + kn);
    bf16x8 a1n = *(const bf16x8*)(Ap + a16 + kn);
    bf16x8 b0n = *(const bf16x8*)(Bp + kn);
    bf16x8 b1n = *(const bf16x8*)(Bp + a16 + kn);
    acc[0][0] = __builtin_amdgcn_mfma_f32_16x16x32_bf16(a0, b0, acc[0][0], 0, 0, 0);
    acc[0][1] = __builtin_amdgcn_mfma_f32_16x16x32_bf16(a0, b1, acc[0][1], 0, 0, 0);
    acc[1][0] = __builtin_amdgcn_mfma_f32_16x16x32_bf16(a1, b0, acc[1][0], 0, 0, 0);
    acc[1][1] = __builtin_amdgcn_mfma_f32_16x16x32_bf16(a1, b1, acc[1][1], 0, 0, 0);
    a0 = a0n; a1 = a1n; b0 = b0n; b1 = b1n;
  }
  acc[0][0] = __builtin_amdgcn_mfma_f32_16x16x32_bf16(a0, b0, acc[0][0], 0, 0, 0);
  acc[0][1] = __builtin_amdgcn_mfma_f32_16x16x32_bf16(a0, b1, acc[0][1], 0, 0, 0);
  acc[1][0] = __builtin_amdgcn_mfma_f32_16x16x32_bf16(a1, b0, acc[1][0], 0, 0, 0);
  acc[1][1] = __builtin_amdgcn_mfma_f32_16x16x32_bf16(a1, b1, acc[1][1], 0, 0, 0);

  const int orow = (l >> 4) * 4;
#pragma unroll
  for (int mi = 0; mi < 2; ++mi)
#pragma unroll
    for (int ni = 0; ni < 2; ++ni) {
      const int col = n0 + ni * 16 + lr;
      float bb = (OUT_MODE == 1) ? bias[col] : 0.f;
#pragma unroll
      for (int r = 0; r < 4; ++r) {
        const int row = m0 + mi * 16 + orow + r;
        float v = acc[mi][ni][r] * scale;
        if (OUT_MODE == 0)
          ((unsigned short*)Cout)[(size_t)row * N + col] = f2b(v);
        else
          ((float*)Cout)[(size_t)row * N + col] = v + bb;
      }
    }
}

// ---------------------------------------------------------------------------
// Flash-style causal attention, bf16 MFMA + fp32 online softmax.
// KVBLK=128 + register prefetch (R26). New in R27:
//  - snake work ordering: balances per-CU work sum under round-robin
//    block->CU assignment ([83,104] steps vs [62,124] for descending LPT)
//  - DPP butterfly reductions (VALU-pipe, no ds chains)
//  - causal mask applied only for t >= ntFull (wave-uniform branch)
// ---------------------------------------------------------------------------
__global__ __launch_bounds__(256, 3)
void attn_fwd_mfma(const unsigned short* __restrict__ Q, const unsigned short* __restrict__ K,
                   const unsigned short* __restrict__ Vt, unsigned short* __restrict__ O) {
  __shared__ __align__(16) unsigned short Ks[2][64 * 64];
  __shared__ __align__(16) unsigned short Vs[2][64 * 64];
  __shared__ __align__(16) unsigned short Ps[4][2 * 16 * 64];

  // snake ordering over the weight-sorted item list
  const int item = blockIdx.x;
  int s;
  if (item < 256)      s = item;         // heaviest, descending
  else if (item < 512) s = 767 - item;   // middle, ascending
  else                 s = item;         // lightest, descending
  const int qt = 63 - s / NHEAD;
  const int h  = s % NHEAD;
  const int q0 = qt * 64;
  const int tid = threadIdx.x;
  const int w = tid >> 6, l = tid & 63;
  const int lr = l & 15, lg = l >> 4;
  const int sr = tid >> 2, sq = tid & 3;   // staging: row, qword base

  // Q fragments (held in registers; scale pre-folded into Q)
  bf16x8 qf[2];
#pragma unroll
  for (int kc = 0; kc < 2; ++kc)
    qf[kc] = *(const bf16x8*)(Q + (size_t)(q0 + w * 16 + lr) * DMODEL + h * HDIM + kc * 32 + lg * 8);

  f32x4 o_acc[4] = {};
  float m_i[4], l_i[4];
#pragma unroll
  for (int r = 0; r < 4; ++r) { m_i[r] = -1e30f; l_i[r] = 0.f; }

  const int nt2    = (qt + 2) >> 1;                                     // 128-wide iterations
  const int ntFull = (64 * qt >= 127) ? ((64 * qt - 127) / 128 + 1) : 0; // fully-unmasked prefix

  us8 kreg[2][2], vreg[2][2];

  // ---- prologue: stage tile 0 (both halves) ----
#pragma unroll
  for (int hh = 0; hh < 2; ++hh)
#pragma unroll
    for (int p = 0; p < 2; ++p) {
      const int qw = sq + p * 4;
      kreg[hh][p] = *(const us8*)(K  + (size_t)(hh * 64 + sr) * DMODEL + h * HDIM + qw * 8);
      vreg[hh][p] = *(const us8*)(Vt + (size_t)(h * HDIM + sr) * S_LEN + hh * 64 + qw * 8);
    }
#pragma unroll
  for (int hh = 0; hh < 2; ++hh)
#pragma unroll
    for (int p = 0; p < 2; ++p) {
      const int qw = sq + p * 4;
      const int sw = (qw * 8) ^ ((sr & 7) * 8);
      *(us8*)(&Ks[hh][sr * 64 + sw]) = kreg[hh][p];
      *(us8*)(&Vs[hh][sr * 64 + sw]) = vreg[hh][p];
    }
  __syncthreads();

  for (int t = 0; t < nt2; ++t) {
    const int k0 = t * 128;
    const bool more = (t + 1 < nt2);
    const bool need_mask = (t >= ntFull);

    // ---- prefetch next 128-kv tile into registers ----
    if (more) {
      const int k0n = k0 + 128;
#pragma unroll
      for (int hh = 0; hh < 2; ++hh)
#pragma unroll
        for (int p = 0; p < 2; ++p) {
          const int qw = sq + p * 4;
          kreg[hh][p] = *(const us8*)(K  + (size_t)(k0n + hh * 64 + sr) * DMODEL + h * HDIM + qw * 8);
          vreg[hh][p] = *(const us8*)(Vt + (size_t)(h * HDIM + sr) * S_LEN + k0n + hh * 64 + qw * 8);
        }
    }

    // ---- S = Q K^T over 128 kv (16 MFMA) ----
    f32x4 sacc[2][4] = {};
#pragma unroll
    for (int hh = 0; hh < 2; ++hh)
#pragma unroll
      for (int kc = 0; kc < 2; ++kc)
#pragma unroll
        for (int cb = 0; cb < 4; ++cb) {
          const int kv = cb * 16 + lr;
          bf16x8 kf = *(const bf16x8*)(&Ks[hh][kv * 64 + ((kc * 32 + lg * 8) ^ ((kv & 7) * 8))]);
          sacc[hh][cb] = __builtin_amdgcn_mfma_f32_16x16x32_bf16(qf[kc], kf, sacc[hh][cb], 0, 0, 0);
        }

    // ---- online softmax: ONE update per 128 kv (8 elems/row) ----
    float p[4][8];
#pragma unroll
    for (int r = 0; r < 4; ++r) {
      const int qg = q0 + w * 16 + lg * 4 + r;
      float sv[8];
#pragma unroll
      for (int hh = 0; hh < 2; ++hh)
#pragma unroll
        for (int cb = 0; cb < 4; ++cb)
          sv[hh * 4 + cb] = sacc[hh][cb][r];
      if (need_mask) {
#pragma unroll
        for (int hh = 0; hh < 2; ++hh)
#pragma unroll
          for (int cb = 0; cb < 4; ++cb) {
            const int kg = k0 + hh * 64 + cb * 16 + lr;
            if (kg > qg) sv[hh * 4 + cb] = -1e30f;
          }
      }
      float mt = fmaxf(fmaxf(fmaxf(sv[0], sv[1]), fmaxf(sv[2], sv[3])),
                       fmaxf(fmaxf(sv[4], sv[5]), fmaxf(sv[6], sv[7])));
      mt = dpp_max16(mt);
      const float mnew = fmaxf(m_i[r], mt);
      const float alpha = __expf(m_i[r] - mnew);
      m_i[r] = mnew;
      float rs = 0.f;
#pragma unroll
      for (int e = 0; e < 8; ++e) { p[r][e] = __expf(sv[e] - mnew); rs += p[r][e]; }
      rs = dpp_sum16(rs);
      l_i[r] = l_i[r] * alpha + rs;
#pragma unroll
      for (int db = 0; db < 4; ++db) o_acc[db][r] *= alpha;
    }

    // ---- P -> bf16, per-wave LDS re-layout (both halves) ----
#pragma unroll
    for (int r = 0; r < 4; ++r) {
      const int qloc = lg * 4 + r;
#pragma unroll
      for (int hh = 0; hh < 2; ++hh)
#pragma unroll
        for (int cb = 0; cb < 4; ++cb) {
          const int kvl = cb * 16 + lr;
          Ps[w][hh * 1024 + qloc * 64 + (kvl ^ ((qloc & 7) * 8))] = f2b(p[r][hh * 4 + cb]);
        }
    }

    // ---- O += P V over 128 kv (16 MFMA) ----
#pragma unroll
    for (int hh = 0; hh < 2; ++hh)
#pragma unroll
      for (int kc = 0; kc < 2; ++kc) {
        bf16x8 pf = *(const bf16x8*)(&Ps[w][hh * 1024 + lr * 64 + ((kc * 32 + lg * 8) ^ ((lr & 7) * 8))]);
#pragma unroll
        for (int db = 0; db < 4; ++db) {
          const int d = db * 16 + lr;
          bf16x8 vf = *(const bf16x8*)(&Vs[hh][d * 64 + ((kc * 32 + lg * 8) ^ ((d & 7) * 8))]);
          o_acc[db] = __builtin_amdgcn_mfma_f32_16x16x32_bf16(pf, vf, o_acc[db], 0, 0, 0);
        }
      }

    __syncthreads();   // all reads of Ks/Vs done
    if (more) {
#pragma unroll
      for (int hh = 0; hh < 2; ++hh)
#pragma unroll
        for (int p = 0; p < 2; ++p) {
          const int qw = sq + p * 4;
          const int sw = (qw * 8) ^ ((sr & 7) * 8);
          *(us8*)(&Ks[hh][sr * 64 + sw]) = kreg[hh][p];
          *(us8*)(&Vs[hh][sr * 64 + sw]) = vreg[hh][p];
        }
      __syncthreads();   // next tile visible
    }
  }

  // ---- epilogue: normalize, store ctx (bf16) ----
#pragma unroll
  for (int r = 0; r < 4; ++r) {
    const float inv = 1.f / l_i[r];
    const int row = q0 + w * 16 + lg * 4 + r;
#pragma unroll
    for (int db = 0; db < 4; ++db)
      O[(size_t)row * DMODEL + h * HDIM + db * 16 + lr] = f2b(o_acc[db][r] * inv);
  }
}

// ---------------------------------------------------------------------------
extern "C" void kernel_launch(void* const* d_in, const int* in_sizes, int n_in,
                              void* d_out, int out_size, void* d_ws, size_t ws_size,
                              hipStream_t stream) {
  const float* x  = (const float*)d_in[0];
  const float* Wq = (const float*)d_in[1];
  const float* Wk = (const float*)d_in[2];
  const float* Wv = (const float*)d_in[3];
  const float* Wo = (const float*)d_in[4];
  const float* bo = (const float*)d_in[5];
  float* out = (float*)d_out;

  const size_t SD = (size_t)S_LEN * DMODEL;   // 3,145,728
  const size_t DD = (size_t)DMODEL * DMODEL;  //   589,824

  unsigned short* xh   = (unsigned short*)d_ws;
  unsigned short* Wqh  = xh   + SD;
  unsigned short* Wkh  = Wqh  + DD;
  unsigned short* Wvh  = Wkh  + DD;
  unsigned short* Woh  = Wvh  + DD;
  unsigned short* Qh   = Woh  + DD;
  unsigned short* Kh   = Qh   + SD;
  unsigned short* Vh   = Kh   + SD;
  unsigned short* Vth  = Vh   + SD;
  unsigned short* ctxh = Vth  + SD;

  const dim3 blk(256);

  cvt_f2b_kern<<<dim3((int)(SD / 8 / 256)), blk, 0, stream>>>(x, xh, (int)SD);
  cvt_f2b4_kern<<<dim3((int)(DD / 8 / 256), 4), blk, 0, stream>>>(
      Wq, Wk, Wv, Wo, Wqh, Wkh, Wvh, Woh, (int)DD);

  const dim3 gg(DMODEL / 64, S_LEN / 64);  // (12, 64)
  gemm_bf16<0><<<gg, blk, 0, stream>>>(xh, Wqh, nullptr, Qh, S_LEN, DMODEL, DMODEL, 0.125f);
  gemm_bf16<0><<<gg, blk, 0, stream>>>(xh, Wkh, nullptr, Kh, S_LEN, DMODEL, DMODEL, 1.0f);
  gemm_bf16<0><<<gg, blk, 0, stream>>>(xh, Wvh, nullptr, Vh, S_LEN, DMODEL, DMODEL, 1.0f);

  transpose_bf16<<<dim3(DMODEL / 64, S_LEN / 64), blk, 0, stream>>>(Vh, Vth);

  attn_fwd_mfma<<<dim3(S_LEN / 64 * NHEAD), blk, 0, stream>>>(Qh, Kh, Vth, ctxh);

  gemm_bf16<1><<<gg, blk, 0, stream>>>(ctxh, Woh, bo, out, S_LEN, DMODEL, DMODEL, 1.0f);
}

// Round 28
// 140.198 us; speedup vs baseline: 7.3030x; 1.6495x over previous
//
#include <hip/hip_runtime.h>
#include <math.h>

static constexpr int S_LEN  = 4096;
static constexpr int DMODEL = 768;
static constexpr int NHEAD  = 12;
static constexpr int HDIM   = 64;

typedef __attribute__((ext_vector_type(8))) short   bf16x8;
typedef __attribute__((ext_vector_type(4))) float   f32x4;
typedef __attribute__((ext_vector_type(8))) unsigned short us8;

__device__ __forceinline__ unsigned short f2b(float f) {
  union { float f; unsigned int u; } v; v.f = f;
  unsigned int u = v.u;
  return (unsigned short)((u + 0x7fffu + ((u >> 16) & 1u)) >> 16);  // RNE
}

// DPP butterfly reduction within 16-lane groups (pure VALU).
__device__ __forceinline__ float dpp_max16(float x) {
  float y;
  y = __int_as_float(__builtin_amdgcn_mov_dpp(__float_as_int(x), 0xB1, 0xf, 0xf, true)); x = fmaxf(x, y);
  y = __int_as_float(__builtin_amdgcn_mov_dpp(__float_as_int(x), 0x4E, 0xf, 0xf, true)); x = fmaxf(x, y);
  y = __int_as_float(__builtin_amdgcn_mov_dpp(__float_as_int(x), 0x124, 0xf, 0xf, true)); x = fmaxf(x, y);
  y = __int_as_float(__builtin_amdgcn_mov_dpp(__float_as_int(x), 0x128, 0xf, 0xf, true)); x = fmaxf(x, y);
  return x;
}
__device__ __forceinline__ float dpp_sum16(float x) {
  float y;
  y = __int_as_float(__builtin_amdgcn_mov_dpp(__float_as_int(x), 0xB1, 0xf, 0xf, true)); x += y;
  y = __int_as_float(__builtin_amdgcn_mov_dpp(__float_as_int(x), 0x4E, 0xf, 0xf, true)); x += y;
  y = __int_as_float(__builtin_amdgcn_mov_dpp(__float_as_int(x), 0x124, 0xf, 0xf, true)); x += y;
  y = __int_as_float(__builtin_amdgcn_mov_dpp(__float_as_int(x), 0x128, 0xf, 0xf, true)); x += y;
  return x;
}

// ---------------------------------------------------------------------------
// fp32 -> bf16 bulk convert
// ---------------------------------------------------------------------------
__global__ __launch_bounds__(256)
void cvt_f2b_kern(const float* __restrict__ in, unsigned short* __restrict__ out, int n) {
  int i = (blockIdx.x * blockDim.x + threadIdx.x) * 8;
  if (i >= n) return;
  float4 a = *(const float4*)(in + i);
  float4 b = *(const float4*)(in + i + 4);
  ushort4 o0; o0.x = f2b(a.x); o0.y = f2b(a.y); o0.z = f2b(a.z); o0.w = f2b(a.w);
  ushort4 o1; o1.x = f2b(b.x); o1.y = f2b(b.y); o1.z = f2b(b.z); o1.w = f2b(b.w);
  *(ushort4*)(out + i)     = o0;
  *(ushort4*)(out + i + 4) = o1;
}

// 4 weight matrices in one launch (blockIdx.y selects the matrix)
__global__ __launch_bounds__(256)
void cvt_f2b4_kern(const float* __restrict__ s0, const float* __restrict__ s1,
                   const float* __restrict__ s2, const float* __restrict__ s3,
                   unsigned short* __restrict__ d0, unsigned short* __restrict__ d1,
                   unsigned short* __restrict__ d2, unsigned short* __restrict__ d3,
                   int n) {
  const float* s; unsigned short* d;
  switch (blockIdx.y) {
    case 0: s = s0; d = d0; break;
    case 1: s = s1; d = d1; break;
    case 2: s = s2; d = d2; break;
    default: s = s3; d = d3; break;
  }
  int i = (blockIdx.x * blockDim.x + threadIdx.x) * 8;
  if (i >= n) return;
  float4 a = *(const float4*)(s + i);
  float4 b = *(const float4*)(s + i + 4);
  ushort4 o0; o0.x = f2b(a.x); o0.y = f2b(a.y); o0.z = f2b(a.z); o0.w = f2b(a.w);
  ushort4 o1; o1.x = f2b(b.x); o1.y = f2b(b.y); o1.z = f2b(b.z); o1.w = f2b(b.w);
  *(ushort4*)(d + i)     = o0;
  *(ushort4*)(d + i + 4) = o1;
}

// ---------------------------------------------------------------------------
// bf16 transpose: in [S][D] -> out [D][S], 64x64 tiles via LDS.
// ---------------------------------------------------------------------------
__global__ __launch_bounds__(256)
void transpose_bf16(const unsigned short* __restrict__ in, unsigned short* __restrict__ out) {
  __shared__ __align__(16) unsigned short Ts[64][72];
  const int d0 = blockIdx.x * 64, s0 = blockIdx.y * 64;
  const int r = threadIdx.x >> 2, q = threadIdx.x & 3;
#pragma unroll
  for (int hh = 0; hh < 2; ++hh) {
    const int c8 = q + hh * 4;
    us8 v = *(const us8*)(in + (size_t)(s0 + r) * DMODEL + d0 + c8 * 8);
    *(us8*)(&Ts[r][c8 * 8]) = v;
  }
  __syncthreads();
#pragma unroll
  for (int hh = 0; hh < 2; ++hh) {
    const int sq = q + hh * 4;
    __align__(16) unsigned short tmp[8];
#pragma unroll
    for (int j = 0; j < 8; ++j) tmp[j] = Ts[sq * 8 + j][r];
    *(us8*)(out + (size_t)(d0 + r) * S_LEN + s0 + sq * 8) = *(us8*)tmp;
  }
}

// ---------------------------------------------------------------------------
// LDS-staged GEMM body: C[M,N] = A[M,K] @ B[N,K]^T, 64x64 tile, BK=64.
// A/B k-panels (8 KB each) staged in LDS with XOR chunk swizzle
// (slot = chunk ^ (row&7)); next panel prefetched to registers during
// compute, ds_write after the drain barrier (attn-proven T14 pattern).
// ---------------------------------------------------------------------------
template<int OUT_MODE>
__device__ __forceinline__
void gemm_body(const unsigned short* __restrict__ A, const unsigned short* __restrict__ B,
               const float* __restrict__ bias, void* __restrict__ Cout,
               int M, int N, int K, float scale, int bx, int by,
               unsigned short* As, unsigned short* Bs) {
  const int l  = threadIdx.x & 63;
  const int w  = threadIdx.x >> 6;
  const int wm = (w >> 1) * 32, wn = (w & 1) * 32;
  const int m0 = by * 64;
  const int n0 = bx * 64;
  const int lr = l & 15, lg = l >> 4;
  const int sr = threadIdx.x >> 2, sq = threadIdx.x & 3;

  f32x4 acc[2][2] = {};
  us8 areg[2], breg[2];

  // prologue: stage k-panel 0
#pragma unroll
  for (int p = 0; p < 2; ++p) {
    const int c = sq + p * 4;
    areg[p] = *(const us8*)(A + (size_t)(m0 + sr) * K + c * 8);
    breg[p] = *(const us8*)(B + (size_t)(n0 + sr) * K + c * 8);
  }
#pragma unroll
  for (int p = 0; p < 2; ++p) {
    const int c = sq + p * 4;
    const int slot = ((c ^ (sr & 7)) * 8);
    *(us8*)(&As[sr * 64 + slot]) = areg[p];
    *(us8*)(&Bs[sr * 64 + slot]) = breg[p];
  }
  __syncthreads();

  const int nsteps = K / 64;  // 12
  for (int t = 0; t < nsteps; ++t) {
    const bool more = (t + 1 < nsteps);
    if (more) {
      const int kn = (t + 1) * 64;
#pragma unroll
      for (int p = 0; p < 2; ++p) {
        const int c = sq + p * 4;
        areg[p] = *(const us8*)(A + (size_t)(m0 + sr) * K + kn + c * 8);
        breg[p] = *(const us8*)(B + (size_t)(n0 + sr) * K + kn + c * 8);
      }
    }
#pragma unroll
    for (int kc = 0; kc < 2; ++kc) {
      const int cr = kc * 4 + lg;
      bf16x8 af[2], bfr[2];
#pragma unroll
      for (int mi = 0; mi < 2; ++mi) {
        const int row = wm + mi * 16 + lr;
        af[mi] = *(const bf16x8*)(&As[row * 64 + ((cr ^ (row & 7)) * 8)]);
      }
#pragma unroll
      for (int ni = 0; ni < 2; ++ni) {
        const int row = wn + ni * 16 + lr;
        bfr[ni] = *(const bf16x8*)(&Bs[row * 64 + ((cr ^ (row & 7)) * 8)]);
      }
#pragma unroll
      for (int mi = 0; mi < 2; ++mi)
#pragma unroll
        for (int ni = 0; ni < 2; ++ni)
          acc[mi][ni] = __builtin_amdgcn_mfma_f32_16x16x32_bf16(af[mi], bfr[ni], acc[mi][ni], 0, 0, 0);
    }
    __syncthreads();
    if (more) {
#pragma unroll
      for (int p = 0; p < 2; ++p) {
        const int c = sq + p * 4;
        const int slot = ((c ^ (sr & 7)) * 8);
        *(us8*)(&As[sr * 64 + slot]) = areg[p];
        *(us8*)(&Bs[sr * 64 + slot]) = breg[p];
      }
      __syncthreads();
    }
  }

  const int orow = (l >> 4) * 4;
#pragma unroll
  for (int mi = 0; mi < 2; ++mi)
#pragma unroll
    for (int ni = 0; ni < 2; ++ni) {
      const int col = n0 + wn + ni * 16 + lr;
      float bb = (OUT_MODE == 1) ? bias[col] : 0.f;
#pragma unroll
      for (int r = 0; r < 4; ++r) {
        const int row = m0 + wm + mi * 16 + orow + r;
        float v = acc[mi][ni][r] * scale;
        if (OUT_MODE == 0)
          ((unsigned short*)Cout)[(size_t)row * N + col] = f2b(v);
        else
          ((float*)Cout)[(size_t)row * N + col] = v + bb;
      }
    }
}

// Fused QKV projection: blockIdx.z selects weight/output/scale.
__global__ __launch_bounds__(256)
void gemm_qkv_lds(const unsigned short* __restrict__ X,
                  const unsigned short* __restrict__ Wq, const unsigned short* __restrict__ Wk,
                  const unsigned short* __restrict__ Wv,
                  unsigned short* __restrict__ Qh, unsigned short* __restrict__ Kh,
                  unsigned short* __restrict__ Vh) {
  __shared__ __align__(16) unsigned short As[64 * 64];
  __shared__ __align__(16) unsigned short Bs[64 * 64];
  const unsigned short* B; unsigned short* C; float scale;
  switch (blockIdx.z) {
    case 0:  B = Wq; C = Qh; scale = 0.125f; break;
    case 1:  B = Wk; C = Kh; scale = 1.0f;   break;
    default: B = Wv; C = Vh; scale = 1.0f;   break;
  }
  gemm_body<0>(X, B, nullptr, C, S_LEN, DMODEL, DMODEL, scale,
               blockIdx.x, blockIdx.y, As, Bs);
}

// Single GEMM (final projection, fp32 out + bias)
__global__ __launch_bounds__(256)
void gemm_lds_f32(const unsigned short* __restrict__ A, const unsigned short* __restrict__ B,
                  const float* __restrict__ bias, float* __restrict__ C) {
  __shared__ __align__(16) unsigned short As[64 * 64];
  __shared__ __align__(16) unsigned short Bs[64 * 64];
  gemm_body<1>(A, B, bias, C, S_LEN, DMODEL, DMODEL, 1.0f,
               blockIdx.x, blockIdx.y, As, Bs);
}

// ---------------------------------------------------------------------------
// Flash-style causal attention (byte-identical to R27 measured build).
// ---------------------------------------------------------------------------
__global__ __launch_bounds__(256, 3)
void attn_fwd_mfma(const unsigned short* __restrict__ Q, const unsigned short* __restrict__ K,
                   const unsigned short* __restrict__ Vt, unsigned short* __restrict__ O) {
  __shared__ __align__(16) unsigned short Ks[2][64 * 64];
  __shared__ __align__(16) unsigned short Vs[2][64 * 64];
  __shared__ __align__(16) unsigned short Ps[4][2 * 16 * 64];

  const int item = blockIdx.x;
  int s;
  if (item < 256)      s = item;
  else if (item < 512) s = 767 - item;
  else                 s = item;
  const int qt = 63 - s / NHEAD;
  const int h  = s % NHEAD;
  const int q0 = qt * 64;
  const int tid = threadIdx.x;
  const int w = tid >> 6, l = tid & 63;
  const int lr = l & 15, lg = l >> 4;
  const int sr = tid >> 2, sq = tid & 3;

  bf16x8 qf[2];
#pragma unroll
  for (int kc = 0; kc < 2; ++kc)
    qf[kc] = *(const bf16x8*)(Q + (size_t)(q0 + w * 16 + lr) * DMODEL + h * HDIM + kc * 32 + lg * 8);

  f32x4 o_acc[4] = {};
  float m_i[4], l_i[4];
#pragma unroll
  for (int r = 0; r < 4; ++r) { m_i[r] = -1e30f; l_i[r] = 0.f; }

  const int nt2    = (qt + 2) >> 1;
  const int ntFull = (64 * qt >= 127) ? ((64 * qt - 127) / 128 + 1) : 0;

  us8 kreg[2][2], vreg[2][2];

#pragma unroll
  for (int hh = 0; hh < 2; ++hh)
#pragma unroll
    for (int p = 0; p < 2; ++p) {
      const int qw = sq + p * 4;
      kreg[hh][p] = *(const us8*)(K  + (size_t)(hh * 64 + sr) * DMODEL + h * HDIM + qw * 8);
      vreg[hh][p] = *(const us8*)(Vt + (size_t)(h * HDIM + sr) * S_LEN + hh * 64 + qw * 8);
    }
#pragma unroll
  for (int hh = 0; hh < 2; ++hh)
#pragma unroll
    for (int p = 0; p < 2; ++p) {
      const int qw = sq + p * 4;
      const int sw = (qw * 8) ^ ((sr & 7) * 8);
      *(us8*)(&Ks[hh][sr * 64 + sw]) = kreg[hh][p];
      *(us8*)(&Vs[hh][sr * 64 + sw]) = vreg[hh][p];
    }
  __syncthreads();

  for (int t = 0; t < nt2; ++t) {
    const int k0 = t * 128;
    const bool more = (t + 1 < nt2);
    const bool need_mask = (t >= ntFull);

    if (more) {
      const int k0n = k0 + 128;
#pragma unroll
      for (int hh = 0; hh < 2; ++hh)
#pragma unroll
        for (int p = 0; p < 2; ++p) {
          const int qw = sq + p * 4;
          kreg[hh][p] = *(const us8*)(K  + (size_t)(k0n + hh * 64 + sr) * DMODEL + h * HDIM + qw * 8);
          vreg[hh][p] = *(const us8*)(Vt + (size_t)(h * HDIM + sr) * S_LEN + k0n + hh * 64 + qw * 8);
        }
    }

    f32x4 sacc[2][4] = {};
#pragma unroll
    for (int hh = 0; hh < 2; ++hh)
#pragma unroll
      for (int kc = 0; kc < 2; ++kc)
#pragma unroll
        for (int cb = 0; cb < 4; ++cb) {
          const int kv = cb * 16 + lr;
          bf16x8 kf = *(const bf16x8*)(&Ks[hh][kv * 64 + ((kc * 32 + lg * 8) ^ ((kv & 7) * 8))]);
          sacc[hh][cb] = __builtin_amdgcn_mfma_f32_16x16x32_bf16(qf[kc], kf, sacc[hh][cb], 0, 0, 0);
        }

    float p[4][8];
#pragma unroll
    for (int r = 0; r < 4; ++r) {
      const int qg = q0 + w * 16 + lg * 4 + r;
      float sv[8];
#pragma unroll
      for (int hh = 0; hh < 2; ++hh)
#pragma unroll
        for (int cb = 0; cb < 4; ++cb)
          sv[hh * 4 + cb] = sacc[hh][cb][r];
      if (need_mask) {
#pragma unroll
        for (int hh = 0; hh < 2; ++hh)
#pragma unroll
          for (int cb = 0; cb < 4; ++cb) {
            const int kg = k0 + hh * 64 + cb * 16 + lr;
            if (kg > qg) sv[hh * 4 + cb] = -1e30f;
          }
      }
      float mt = fmaxf(fmaxf(fmaxf(sv[0], sv[1]), fmaxf(sv[2], sv[3])),
                       fmaxf(fmaxf(sv[4], sv[5]), fmaxf(sv[6], sv[7])));
      mt = dpp_max16(mt);
      const float mnew = fmaxf(m_i[r], mt);
      const float alpha = __expf(m_i[r] - mnew);
      m_i[r] = mnew;
      float rs = 0.f;
#pragma unroll
      for (int e = 0; e < 8; ++e) { p[r][e] = __expf(sv[e] - mnew); rs += p[r][e]; }
      rs = dpp_sum16(rs);
      l_i[r] = l_i[r] * alpha + rs;
#pragma unroll
      for (int db = 0; db < 4; ++db) o_acc[db][r] *= alpha;
    }

#pragma unroll
    for (int r = 0; r < 4; ++r) {
      const int qloc = lg * 4 + r;
#pragma unroll
      for (int hh = 0; hh < 2; ++hh)
#pragma unroll
        for (int cb = 0; cb < 4; ++cb) {
          const int kvl = cb * 16 + lr;
          Ps[w][hh * 1024 + qloc * 64 + (kvl ^ ((qloc & 7) * 8))] = f2b(p[r][hh * 4 + cb]);
        }
    }

#pragma unroll
    for (int hh = 0; hh < 2; ++hh)
#pragma unroll
      for (int kc = 0; kc < 2; ++kc) {
        bf16x8 pf = *(const bf16x8*)(&Ps[w][hh * 1024 + lr * 64 + ((kc * 32 + lg * 8) ^ ((lr & 7) * 8))]);
#pragma unroll
        for (int db = 0; db < 4; ++db) {
          const int d = db * 16 + lr;
          bf16x8 vf = *(const bf16x8*)(&Vs[hh][d * 64 + ((kc * 32 + lg * 8) ^ ((d & 7) * 8))]);
          o_acc[db] = __builtin_amdgcn_mfma_f32_16x16x32_bf16(pf, vf, o_acc[db], 0, 0, 0);
        }
      }

    __syncthreads();
    if (more) {
#pragma unroll
      for (int hh = 0; hh < 2; ++hh)
#pragma unroll
        for (int p = 0; p < 2; ++p) {
          const int qw = sq + p * 4;
          const int sw = (qw * 8) ^ ((sr & 7) * 8);
          *(us8*)(&Ks[hh][sr * 64 + sw]) = kreg[hh][p];
          *(us8*)(&Vs[hh][sr * 64 + sw]) = vreg[hh][p];
        }
      __syncthreads();
    }
  }

#pragma unroll
  for (int r = 0; r < 4; ++r) {
    const float inv = 1.f / l_i[r];
    const int row = q0 + w * 16 + lg * 4 + r;
#pragma unroll
    for (int db = 0; db < 4; ++db)
      O[(size_t)row * DMODEL + h * HDIM + db * 16 + lr] = f2b(o_acc[db][r] * inv);
  }
}

// ---------------------------------------------------------------------------
extern "C" void kernel_launch(void* const* d_in, const int* in_sizes, int n_in,
                              void* d_out, int out_size, void* d_ws, size_t ws_size,
                              hipStream_t stream) {
  const float* x  = (const float*)d_in[0];
  const float* Wq = (const float*)d_in[1];
  const float* Wk = (const float*)d_in[2];
  const float* Wv = (const float*)d_in[3];
  const float* Wo = (const float*)d_in[4];
  const float* bo = (const float*)d_in[5];
  float* out = (float*)d_out;

  const size_t SD = (size_t)S_LEN * DMODEL;   // 3,145,728
  const size_t DD = (size_t)DMODEL * DMODEL;  //   589,824

  unsigned short* xh   = (unsigned short*)d_ws;
  unsigned short* Wqh  = xh   + SD;
  unsigned short* Wkh  = Wqh  + DD;
  unsigned short* Wvh  = Wkh  + DD;
  unsigned short* Woh  = Wvh  + DD;
  unsigned short* Qh   = Woh  + DD;
  unsigned short* Kh   = Qh   + SD;
  unsigned short* Vh   = Kh   + SD;
  unsigned short* Vth  = Vh   + SD;
  unsigned short* ctxh = Vth  + SD;

  const dim3 blk(256);

  cvt_f2b_kern<<<dim3((int)(SD / 8 / 256)), blk, 0, stream>>>(x, xh, (int)SD);
  cvt_f2b4_kern<<<dim3((int)(DD / 8 / 256), 4), blk, 0, stream>>>(
      Wq, Wk, Wv, Wo, Wqh, Wkh, Wvh, Woh, (int)DD);

  gemm_qkv_lds<<<dim3(DMODEL / 64, S_LEN / 64, 3), blk, 0, stream>>>(
      xh, Wqh, Wkh, Wvh, Qh, Kh, Vh);

  transpose_bf16<<<dim3(DMODEL / 64, S_LEN / 64), blk, 0, stream>>>(Vh, Vth);

  attn_fwd_mfma<<<dim3(S_LEN / 64 * NHEAD), blk, 0, stream>>>(Qh, Kh, Vth, ctxh);

  gemm_lds_f32<<<dim3(DMODEL / 64, S_LEN / 64), blk, 0, stream>>>(ctxh, Woh, bo, out);
}